// Round 1
// baseline (603.273 us; speedup 1.0000x reference)
//
#include <hip/hip_runtime.h>

constexpr int NUM = 1000000;
constexpr int DIM = 128;

// Mueller hash with torch/numpy int64 semantics: arithmetic shifts,
// wrapping 64-bit multiply (2nd mul exceeds 2^63 -> must wrap via uint64).
__device__ __forceinline__ int bloom_idx(long long t) {
    long long s = t;
    s = (long long)(((unsigned long long)((s >> 16) ^ s)) * 73244475ull);
    s = (long long)(((unsigned long long)((s >> 16) ^ s)) * 73244475ull);
    s = (s >> 16) ^ s;
    // jnp.mod semantics: result has sign of divisor (non-negative here)
    long long m = s % (long long)NUM;
    if (m < 0) m += NUM;
    return (int)m;
}

// One wave (64 lanes) = TWO tokens.
// Lanes 0-15 hold the 16 probe indices: token = lane>>3, probe = lane&7
// (every lane computes its slot; only 0-15 are shfl sources).
// Each gather instruction fetches TWO rows at once:
//   half h = lane>>5 covers row (2j + h); 32 lanes x 16 B = 512 B per row,
//   1024 B per global_load_dwordx4. 8 loads replace the previous 16 dwordx2.
// Loads j=0..3 accumulate token0 (acc0), j=4..7 token1 (acc1).
// Final combine: each half-wave needs its own token's other-half partial:
//   p = own-token partial, q = other accumulator; shfl_xor(q,32) delivers
//   exactly the missing half (low lanes get acc0[hi], high lanes acc1[lo]).
// Store: lane*16 B at out+token0*DIM = one contiguous 1024 B dwordx4
// covering both tokens' 128-float rows.
__global__ __launch_bounds__(256) void bloom_embed_kernel(
        const int* __restrict__ t,
        const float* __restrict__ W,
        float* __restrict__ out,
        int n_tokens) {
    const int gtid   = blockIdx.x * blockDim.x + threadIdx.x;
    const int wave   = gtid >> 6;
    const int lane   = threadIdx.x & 63;
    const int token0 = wave * 2;
    if (token0 >= n_tokens) return;
    const bool have2 = (token0 + 1) < n_tokens;

    const int toff = (lane >> 3) & 1;                 // which token this slot hashes
    const long long tv = (long long)t[have2 ? (token0 + toff) : token0];
    const int my_idx = bloom_idx(tv + (long long)(lane & 7));

    const int half = lane >> 5;                       // 0: rows 2j, 1: rows 2j+1
    const int col  = lane & 31;                       // float4 column within row

    float4 acc0 = make_float4(0.f, 0.f, 0.f, 0.f);
    float4 acc1 = make_float4(0.f, 0.f, 0.f, 0.f);
#pragma unroll
    for (int j = 0; j < 8; ++j) {
        const int idx = __shfl(my_idx, 2 * j + half); // wave-wide bcast
        const float4 v = *(const float4*)(W + (size_t)idx * DIM + col * 4);
        if (j < 4) {
            acc0.x += v.x; acc0.y += v.y; acc0.z += v.z; acc0.w += v.w;
        } else {
            acc1.x += v.x; acc1.y += v.y; acc1.z += v.z; acc1.w += v.w;
        }
    }

    // p = this half-wave's own-token partial; q's shfl_xor(32) image is the
    // missing half of the own token (see comment block above).
    const float4 p = half ? acc1 : acc0;
    const float4 q = half ? acc0 : acc1;
    float4 r;
    r.x = __shfl_xor(q.x, 32);
    r.y = __shfl_xor(q.y, 32);
    r.z = __shfl_xor(q.z, 32);
    r.w = __shfl_xor(q.w, 32);

    float4 val;
    val.x = (p.x + r.x) * 0.125f;
    val.y = (p.y + r.y) * 0.125f;
    val.z = (p.z + r.z) * 0.125f;
    val.w = (p.w + r.w) * 0.125f;

    if (have2 || half == 0) {
        ((float4*)(out + (size_t)token0 * DIM))[lane] = val;
    }
}

extern "C" void kernel_launch(void* const* d_in, const int* in_sizes, int n_in,
                              void* d_out, int out_size, void* d_ws, size_t ws_size,
                              hipStream_t stream) {
    const int*   t = (const int*)d_in[0];     // 32*2048 = 65536 tokens
    const float* W = (const float*)d_in[1];   // [1e6, 128] fp32
    float*     out = (float*)d_out;           // [65536, 128] fp32

    const int n_tokens = in_sizes[0];         // 65536
    const int n_waves  = (n_tokens + 1) / 2;  // 2 tokens per wave
    const int waves_per_block = 256 / 64;     // 4 waves -> 8 tokens per block
    const int blocks = (n_waves + waves_per_block - 1) / waves_per_block;

    bloom_embed_kernel<<<blocks, 256, 0, stream>>>(t, W, out, n_tokens);
}

// Round 2
// 592.557 us; speedup vs baseline: 1.0181x; 1.0181x over previous
//
#include <hip/hip_runtime.h>

constexpr int NUM = 1000000;
constexpr int DIM = 128;

typedef float f4 __attribute__((ext_vector_type(4)));
typedef float f2 __attribute__((ext_vector_type(2)));

// Mueller hash with torch/numpy int64 semantics: arithmetic shifts,
// wrapping 64-bit multiply (2nd mul exceeds 2^63 -> must wrap via uint64).
__device__ __forceinline__ int bloom_idx(long long t) {
    long long s = t;
    s = (long long)(((unsigned long long)((s >> 16) ^ s)) * 73244475ull);
    s = (long long)(((unsigned long long)((s >> 16) ^ s)) * 73244475ull);
    s = (s >> 16) ^ s;
    // jnp.mod semantics: result has sign of divisor (non-negative here)
    long long m = s % (long long)NUM;
    if (m < 0) m += NUM;
    return (int)m;
}

__device__ __forceinline__ f4 xor32(f4 a) {
    f4 r;
    r.x = __shfl_xor(a.x, 32);
    r.y = __shfl_xor(a.y, 32);
    r.z = __shfl_xor(a.z, 32);
    r.w = __shfl_xor(a.w, 32);
    return r;
}

// One wave (64 lanes) = FOUR tokens.
// 32 probe slots: slot s (held by lane s, s<32): token = s>>3, probe k = s&7.
// Gather j=0..15: one dwordx4 instruction fetches TWO rows (slots 2j, 2j+1):
//   lanes 0-31 cover slot 2j's row, lanes 32-63 slot 2j+1's row,
//   32 lanes x 16 B = 512 B per row, 1024 B per instruction.
// Slots 2j and 2j+1 always belong to the same token (j>>2), so the
// accumulator index is compile-time static under full unroll.
// 16 independent nontemporal loads in flight per wave (2x round-1 MLP);
// NT flag = no L1 allocate (W rows are touched ~1.3x, reuse lives in L2/L3).
// Combine: acc_t + shfl_xor(acc_t, 32) completes each token's row on all
// lanes (halves hold even/odd-slot partials of the same columns).
// Store: two contiguous 1024 B NT dwordx4 stores cover all 4 output rows.
__global__ __launch_bounds__(256) void bloom_embed_kernel(
        const int* __restrict__ t,
        const float* __restrict__ W,
        float* __restrict__ out,
        int n_tokens) {
    const int gtid   = blockIdx.x * blockDim.x + threadIdx.x;
    const int wave   = gtid >> 6;
    const int lane   = threadIdx.x & 63;
    const int token0 = wave * 4;
    if (token0 >= n_tokens) return;

    if (token0 + 3 < n_tokens) {
        const int slot = lane & 31;
        const int toff = slot >> 3;                       // token within quad
        const long long tv = (long long)t[token0 + toff];
        const int my_idx = bloom_idx(tv + (long long)(slot & 7));

        const int half = lane >> 5;                       // which row of the pair
        const int col  = lane & 31;                       // float4 column in row

        f4 acc0 = {0.f, 0.f, 0.f, 0.f};
        f4 acc1 = {0.f, 0.f, 0.f, 0.f};
        f4 acc2 = {0.f, 0.f, 0.f, 0.f};
        f4 acc3 = {0.f, 0.f, 0.f, 0.f};
#pragma unroll
        for (int j = 0; j < 16; ++j) {
            const int idx = __shfl(my_idx, 2 * j + half); // wave-wide bcast
            const f4 v = __builtin_nontemporal_load(
                (const f4*)(W + (size_t)idx * DIM) + col);
            switch (j >> 2) {                             // compile-time per j
                case 0: acc0 += v; break;
                case 1: acc1 += v; break;
                case 2: acc2 += v; break;
                default: acc3 += v; break;
            }
        }

        const f4 v0 = (acc0 + xor32(acc0)) * 0.125f;
        const f4 v1 = (acc1 + xor32(acc1)) * 0.125f;
        const f4 v2 = (acc2 + xor32(acc2)) * 0.125f;
        const f4 v3 = (acc3 + xor32(acc3)) * 0.125f;

        // Store A: tokens 0-1 (rows are contiguous), store B: tokens 2-3.
        // lane<32 writes token {0,2} col lane, lane>=32 token {1,3} col lane&31.
        const f4 sA = half ? v1 : v0;
        const f4 sB = half ? v3 : v2;
        f4* dst = (f4*)(out + (size_t)token0 * DIM);
        __builtin_nontemporal_store(sA, dst + lane);
        __builtin_nontemporal_store(sB, dst + 64 + lane);
    } else {
        // Tail: up to 3 leftover tokens, round-0 style (float2 per lane).
        for (int token = token0; token < n_tokens; ++token) {
            const long long tv = (long long)t[token];
            const int my_idx = bloom_idx(tv + (long long)(lane & 7));
            f2 acc = {0.f, 0.f};
#pragma unroll
            for (int k = 0; k < 8; ++k) {
                const int idx = __shfl(my_idx, k);
                const f2 v = *((const f2*)(W + (size_t)idx * DIM) + lane);
                acc += v;
            }
            acc *= 0.125f;
            *((f2*)(out + (size_t)token * DIM) + lane) = acc;
        }
    }
}

extern "C" void kernel_launch(void* const* d_in, const int* in_sizes, int n_in,
                              void* d_out, int out_size, void* d_ws, size_t ws_size,
                              hipStream_t stream) {
    const int*   t = (const int*)d_in[0];     // 32*2048 = 65536 tokens
    const float* W = (const float*)d_in[1];   // [1e6, 128] fp32
    float*     out = (float*)d_out;           // [65536, 128] fp32

    const int n_tokens = in_sizes[0];         // 65536
    const int n_waves  = (n_tokens + 3) / 4;  // 4 tokens per wave
    const int waves_per_block = 256 / 64;     // 4 waves -> 16 tokens per block
    const int blocks = (n_waves + waves_per_block - 1) / waves_per_block;

    bloom_embed_kernel<<<blocks, 256, 0, stream>>>(t, W, out, n_tokens);
}